// Round 17
// baseline (133.216 us; speedup 1.0000x reference)
//
#include <hip/hip_runtime.h>
#include <hip/hip_bf16.h>

using bf16 = __hip_bfloat16;
typedef __attribute__((ext_vector_type(8))) __bf16 bf16x8;
typedef __attribute__((ext_vector_type(4))) float f32x4;

static constexpr int T = 4096, DIM = 768, H = 6, D = 128, N3 = 2304;
static constexpr int PPH = 280;                    // stored partials per head (qt>=8)
static constexpr float kEps = 1.1920929e-07f;
static constexpr float kC1 = 0.12f * 1.44269504f;  // kScale*log2(e), folded into Q
static constexpr float kTHR = 11.54f;              // defer threshold, folded domain (= 8*log2e)

__device__ __forceinline__ void gll16(const bf16* g, bf16* l) {
  __builtin_amdgcn_global_load_lds((const __attribute__((address_space(1))) void*)g,
                                   (__attribute__((address_space(3))) void*)l, 16, 0, 0);
}

// sum_{q'<qt} ((q'>>3)+1)
__device__ __forceinline__ int pre_qt(int qt) {
  const int k = qt >> 3, rr = qt & 7;
  return qt + 4 * k * (k - 1) + rr * k;
}

// fused fp32->bf16 converts (x, qkv_w, cproj) + rotary table build
__global__ __launch_bounds__(256) void prep(const float* __restrict__ x,
                                            const float* __restrict__ qkv_w,
                                            const float* __restrict__ cproj,
                                            bf16* __restrict__ xb, bf16* __restrict__ wb,
                                            bf16* __restrict__ cb, float2* __restrict__ tab) {
  const int NBX = T * DIM / 2048, NBW = N3 * DIM / 2048, NBC = DIM * DIM / 2048;
  int b = blockIdx.x;
  const int tid = threadIdx.x;
  if (b < NBX + NBW + NBC) {
    const float* in;
    bf16* out;
    if (b < NBX) { in = x; out = xb; }
    else if (b < NBX + NBW) { in = qkv_w; out = wb; b -= NBX; }
    else { in = cproj; out = cb; b -= NBX + NBW; }
    const int i = (b * 256 + tid) * 8;
    const float4 a = *(const float4*)(in + i);
    const float4 c = *(const float4*)(in + i + 4);
    bf16 t[8] = {(bf16)a.x, (bf16)a.y, (bf16)a.z, (bf16)a.w,
                 (bf16)c.x, (bf16)c.y, (bf16)c.z, (bf16)c.w};
    *(int4*)(out + i) = *(const int4*)t;
  } else {
    b -= NBX + NBW + NBC;
    const int i = b * 256 + tid;  // T*32 total
    const int t = i >> 5, j = i & 31;
    const float af = exp2f(-10.f * (float)j * (1.f / 31.f));
    float s, c;
    sincosf((float)t * af, &s, &c);
    tab[i] = make_float2(c, s);
  }
}

// GEMM1 fused with qkv post-processing. Tile 64x128 = 64 t-rows x ONE head-slice
// (slice = blockIdx.x: 0-5 q-heads, 6-11 k-heads, 12-17 v-heads). After the
// K-loop, acc -> LDS tile [64][137] and the epilogue does RMS+rotary (q,k) or
// lambda-mix+transpose (v). qkv never touches HBM.
__global__ __launch_bounds__(256, 4) void gemm_qkv(const bf16* __restrict__ A,
                                                   const bf16* __restrict__ B,
                                                   const float2* __restrict__ tab,
                                                   const float* __restrict__ ve,
                                                   const float* __restrict__ lam,
                                                   bf16* __restrict__ qb,
                                                   bf16* __restrict__ kb,
                                                   bf16* __restrict__ vt) {
  __shared__ bf16 sh[12288];  // lA[64][64] @0 | lB[128][64] @4096; then tile[64][137]
  const int tid = threadIdx.x, lane = tid & 63, wid = tid >> 6;
  const int slice = blockIdx.x;         // 0..17
  const int brow = blockIdx.y * 64;
  const int bcol = slice * 128;
  const int wm = (wid >> 1) * 32, wn = (wid & 1) * 64;
  const int r = lane & 15, g = lane >> 4;
  f32x4 acc[2][4] = {};
  const int lrow = lane >> 3;
  const int scol = (lane & 7) * 8;
  const bf16* gA = A + (long)(brow + wid * 16 + lrow) * DIM + scol;
  const bf16* gB = B + (long)(bcol + wid * 32 + lrow) * DIM + scol;
  for (int k0 = 0; k0 < DIM; k0 += 64) {
    __syncthreads();
#pragma unroll
    for (int i = 0; i < 2; ++i)
      gll16(gA + (long)i * 8 * DIM + k0, sh + (wid * 16 + i * 8) * 64);
#pragma unroll
    for (int i = 0; i < 4; ++i)
      gll16(gB + (long)i * 8 * DIM + k0, sh + 4096 + (wid * 32 + i * 8) * 64);
    __syncthreads();
#pragma unroll
    for (int kk = 0; kk < 2; ++kk) {
      bf16x8 af[2], bfr[4];
#pragma unroll
      for (int m = 0; m < 2; ++m)
        af[m] = *(const bf16x8*)(sh + (wm + m * 16 + r) * 64 + kk * 32 + g * 8);
#pragma unroll
      for (int n = 0; n < 4; ++n)
        bfr[n] = *(const bf16x8*)(sh + 4096 + (wn + n * 16 + r) * 64 + kk * 32 + g * 8);
#pragma unroll
      for (int m = 0; m < 2; ++m)
#pragma unroll
        for (int n = 0; n < 4; ++n)
          acc[m][n] = __builtin_amdgcn_mfma_f32_16x16x32_bf16(af[m], bfr[n], acc[m][n], 0, 0, 0);
    }
  }
  __syncthreads();  // all waves done reading lA/lB before tile overlay
#pragma unroll
  for (int m = 0; m < 2; ++m)
#pragma unroll
    for (int n = 0; n < 4; ++n)
#pragma unroll
      for (int q = 0; q < 4; ++q)
        sh[(wm + m * 16 + g * 4 + q) * 137 + wn + n * 16 + r] = (bf16)acc[m][n][q];
  __syncthreads();
  const int type = slice / 6, h = slice % 6;
  if (type < 2) {  // q/k: RMS-norm + rotary. 4 threads/row, 16 (d, d+64) pairs each.
    const int row = tid >> 2, p0 = (tid & 3) * 16;
    const int t = brow + row;
    float x1[16], x2[16];
    float ss = 0.f;
#pragma unroll
    for (int j = 0; j < 16; ++j) {
      x1[j] = __bfloat162float(sh[row * 137 + p0 + j]);
      x2[j] = __bfloat162float(sh[row * 137 + p0 + 64 + j]);
      ss += x1[j] * x1[j] + x2[j] * x2[j];
    }
    ss += __shfl_xor(ss, 1);
    ss += __shfl_xor(ss, 2);
    const float sc = rsqrtf(ss * (1.f / 128.f) + kEps) * (type == 0 ? kC1 : 1.f);
    bf16 y1[16], y2[16];
#pragma unroll
    for (int j = 0; j < 16; ++j) {
      float c = 1.f, s = 0.f;
      if (p0 + j < 32) { const float2 cs = tab[t * 32 + p0 + j]; c = cs.x; s = cs.y; }
      const float a = x1[j] * sc, b = x2[j] * sc;
      y1[j] = (bf16)(a * c + b * s);
      y2[j] = (bf16)(b * c - a * s);
    }
    bf16* dst = (type == 0 ? qb : kb) + ((long)h * T + t) * D + p0;
    *(int4*)(dst) = *(const int4*)&y1[0];
    *(int4*)(dst + 8) = *(const int4*)&y1[8];
    *(int4*)(dst + 64) = *(const int4*)&y2[0];
    *(int4*)(dst + 72) = *(const int4*)&y2[8];
  } else {  // v: v = l0*v + l1*ve, then transpose to (h, d, t)
    const float l0 = lam[0], l1 = lam[1];
    const int row = tid >> 2, seg = (tid & 3) * 32;
    const float* vs = ve + (long)(brow + row) * DIM + h * D + seg;
#pragma unroll
    for (int j = 0; j < 32; j += 4) {
      const float4 e = *(const float4*)(vs + j);
      const float ef[4] = {e.x, e.y, e.z, e.w};
#pragma unroll
      for (int u = 0; u < 4; ++u) {
        const int c = seg + j + u;
        sh[row * 137 + c] = (bf16)(l0 * __bfloat162float(sh[row * 137 + c]) + l1 * ef[u]);
      }
    }
    __syncthreads();
    const int d = tid >> 1, half = tid & 1;
    bf16 outr[32];
#pragma unroll
    for (int j = 0; j < 32; ++j) outr[j] = sh[(half * 32 + j) * 137 + d];
    bf16* dst = vt + ((long)h * D + d) * T + brow + half * 32;
#pragma unroll
    for (int c = 0; c < 4; ++c)
      *(int4*)(dst + c * 8) = *(const int4*)&outr[c * 8];
  }
}

// Output projection GEMM: C(MxN) = A(MxK) * B(NxK)^T. BM=64 x BN=64 tile,
// 16KB LDS, grid (N/64, M/64) = 768 blocks -> ~3 blocks/CU.
template <typename CT>
__global__ __launch_bounds__(256, 4) void gemm_bt(const bf16* __restrict__ A,
                                                  const bf16* __restrict__ B,
                                                  CT* __restrict__ C,
                                                  int M, int N, int K) {
  __shared__ bf16 lA[64][64];
  __shared__ bf16 lB[64][64];
  const int tid = threadIdx.x, lane = tid & 63, wid = tid >> 6;
  const int brow = blockIdx.y * 64, bcol = blockIdx.x * 64;
  const int wm = (wid >> 1) * 32, wn = (wid & 1) * 32;
  const int r = lane & 15, g = lane >> 4;
  f32x4 acc[2][2] = {};
  const int lrow = lane >> 3;
  const int scol = (lane & 7) * 8;
  const bf16* gA = A + (long)(brow + wid * 16 + lrow) * K + scol;
  const bf16* gB = B + (long)(bcol + wid * 16 + lrow) * K + scol;
  for (int k0 = 0; k0 < K; k0 += 64) {
    __syncthreads();
#pragma unroll
    for (int i = 0; i < 2; ++i) {
      gll16(gA + (long)i * 8 * K + k0, &lA[wid * 16 + i * 8][0]);
      gll16(gB + (long)i * 8 * K + k0, &lB[wid * 16 + i * 8][0]);
    }
    __syncthreads();
#pragma unroll
    for (int kk = 0; kk < 2; ++kk) {
      bf16x8 af[2], bfr[2];
#pragma unroll
      for (int m = 0; m < 2; ++m)
        af[m] = *(const bf16x8*)&lA[wm + m * 16 + r][kk * 32 + g * 8];
#pragma unroll
      for (int n = 0; n < 2; ++n)
        bfr[n] = *(const bf16x8*)&lB[wn + n * 16 + r][kk * 32 + g * 8];
#pragma unroll
      for (int m = 0; m < 2; ++m)
#pragma unroll
        for (int n = 0; n < 2; ++n)
          acc[m][n] = __builtin_amdgcn_mfma_f32_16x16x32_bf16(af[m], bfr[n], acc[m][n], 0, 0, 0);
    }
  }
  const int crow = brow + wm + g * 4;
  const int ccol = bcol + wn + r;
#pragma unroll
  for (int m = 0; m < 2; ++m)
#pragma unroll
    for (int n = 0; n < 2; ++n)
#pragma unroll
      for (int q = 0; q < 4; ++q)
        C[(long)(crow + m * 16 + q) * N + ccol + n * 16] = (CT)acc[m][n][q];
}

// Flash-style causal attention. 512-thread block = 128-row q-supertile (8 waves).
// KVBLK=64 single-buffered gll16 staging, chunks of 8 tiles. P-bounce now
// ALIASES Kl (Kl is dead between the QK reads and STAGE): LDS 48KB -> 32KB ->
// 4 blocks/CU (wave-limited) and 864 blocks fit one residency round. Costs one
// extra barrier per tile, placed where vmcnt is already 0 (cheap sync).
__global__ __launch_bounds__(512, 4) void attn(const bf16* __restrict__ qb,
                                               const bf16* __restrict__ kb,
                                               const bf16* __restrict__ vt,
                                               bf16* __restrict__ po,
                                               float* __restrict__ pm,
                                               float* __restrict__ ps,
                                               bf16* __restrict__ yb) {
  __shared__ bf16 Kl[64][128];   // K tile; per-wave 1024-elem P segments alias it
  __shared__ bf16 Vl[128][64];
  const int bid = blockIdx.x;
  const int h = bid % H;
  const int fi = bid / H;
  int s = 31, ci = 0, acc0 = 0;          // heavy-first band decode
  for (int ss = 31; ss >= 0; --ss) {
    const int n = (ss >> 2) + 1;
    if (fi < acc0 + n) { s = ss; ci = fi - acc0; break; }
    acc0 += n;
  }
  const int tid = threadIdx.x, lane = tid & 63, w = tid >> 6;  // w in 0..7
  const int r = lane & 15, g = lane >> 4;
  const int qt = 2 * s + (w >> 2);       // this wave's q-tile
  const int wrow = (w & 3) * 16;         // row offset within q-tile
  const int ts = ci * 8;
  const int te = min(ts + 8, 2 * s + 2);

  bf16x8 qf[4];
#pragma unroll
  for (int kk = 0; kk < 4; ++kk)
    qf[kk] = *(const bf16x8*)(qb + ((long)h * T + qt * 64 + wrow + r) * D + kk * 32 + g * 8);
  f32x4 o[8] = {};
  float m[4], sl[4];
#pragma unroll
  for (int q = 0; q < 4; ++q) { m[q] = -1e30f; sl[q] = 0.f; }

  auto STAGE = [&](int t) {
    const int kv0 = t * 64;
#pragma unroll
    for (int i = 0; i < 2; ++i) {
      const int seg = w * 2 + i;         // 16 segs of 1KB each for K and V
      {  // K: 64 rows x 128 cols; seg = 4 rows of 256B
        const int lr = seg * 4 + (lane >> 4);
        const int cs = (lane & 15) ^ (lr & 7);
        gll16(kb + ((long)h * T + kv0 + lr) * D + cs * 8,
              (bf16*)&Kl[0][0] + seg * 512);
      }
      {  // V: 128 rows x 64 cols; seg = 8 rows of 128B
        const int lr = seg * 8 + (lane >> 3);
        const int cs = (lane & 7) ^ (lr & 7);
        gll16(vt + ((long)h * D + lr) * T + kv0 + cs * 8,
              (bf16*)&Vl[0][0] + seg * 512);
      }
    }
  };

  STAGE(ts);
  __syncthreads();
  for (int tt = ts; tt < te; ++tt) {
    const bool act = (tt <= qt);         // wave-uniform; A-waves skip last tile
    f32x4 st4[4];
    if (act) {
      const bf16* Kb = (const bf16*)&Kl[0][0];
      __builtin_amdgcn_s_setprio(1);
#pragma unroll
      for (int stt = 0; stt < 4; ++stt) {
        f32x4 a = {};
        const int lrk = stt * 16 + r;
#pragma unroll
        for (int kk = 0; kk < 4; ++kk) {
          const bf16x8 kf = *(const bf16x8*)(Kb + lrk * 128 + (((kk * 4 + g) ^ (lrk & 7)) * 8));
          a = __builtin_amdgcn_mfma_f32_16x16x32_bf16(qf[kk], kf, a, 0, 0, 0);
        }
        st4[stt] = a;
      }
      __builtin_amdgcn_s_setprio(0);
      if (tt == qt) {  // diagonal tile: causal mask
        const int qgl = qt * 64 + wrow + 4 * g;
#pragma unroll
        for (int stt = 0; stt < 4; ++stt)
#pragma unroll
          for (int q = 0; q < 4; ++q)
            if (tt * 64 + stt * 16 + r > qgl + q) st4[stt][q] = -1e30f;
      }
      float mx[4];
#pragma unroll
      for (int q = 0; q < 4; ++q)
        mx[q] = fmaxf(fmaxf(st4[0][q], st4[1][q]), fmaxf(st4[2][q], st4[3][q]));
      const float dd = fmaxf(fmaxf(mx[0] - m[0], mx[1] - m[1]),
                             fmaxf(mx[2] - m[2], mx[3] - m[3]));
      if (__any(dd > kTHR)) {  // rare: full max-reduce + rescale
#pragma unroll
        for (int off = 1; off < 16; off <<= 1)
#pragma unroll
          for (int q = 0; q < 4; ++q) mx[q] = fmaxf(mx[q], __shfl_xor(mx[q], off));
#pragma unroll
        for (int q = 0; q < 4; ++q) {
          const float nm = fmaxf(m[q], mx[q]);
          const float al = exp2f(m[q] - nm);
          m[q] = nm;
          sl[q] *= al;
#pragma unroll
          for (int nn = 0; nn < 8; ++nn) o[nn][q] *= al;
        }
      }
      // P = exp2(st - m), scale pre-folded into Q. Explicit subtract (NOT fma
      // with precomputed m-term): masked rows have st=m=-1e30; fma residue can
      // reach +-2^74 -> exp2 -> inf -> 0*inf = NaN in the merge.
#pragma unroll
      for (int stt = 0; stt < 4; ++stt)
#pragma unroll
        for (int q = 0; q < 4; ++q)
          st4[stt][q] = exp2f(st4[stt][q] - m[q]);
#pragma unroll
      for (int q = 0; q < 4; ++q)
        sl[q] += (st4[0][q] + st4[1][q]) + (st4[2][q] + st4[3][q]);
    }
    // Barrier A: every wave's QK reads of Kl are complete -> Kl space is free
    // for the P bounce. vmcnt is already 0 here (no vmem since the last STAGE
    // drain), so this barrier is a cheap execution sync only. Outside the act
    // guard: inactive waves must participate (no divergent barrier).
    __syncthreads();
    if (act) {
      bf16* Pb = (bf16*)&Kl[0][0] + w * 1024;   // 16x64 bf16 per wave, aliases Kl
#pragma unroll
      for (int stt = 0; stt < 4; ++stt)
#pragma unroll
        for (int q = 0; q < 4; ++q) {
          const int rw = 4 * g + q;
          Pb[rw * 64 + ((stt * 16 + r) ^ ((rw & 7) << 3))] = (bf16)st4[stt][q];
        }
      bf16x8 pf[2];
#pragma unroll
      for (int kk = 0; kk < 2; ++kk)
        pf[kk] = *(const bf16x8*)(Pb + r * 64 + (((kk * 4 + g) ^ (r & 7)) * 8));
      const bf16* Vb = (const bf16*)&Vl[0][0];
      __builtin_amdgcn_s_setprio(1);
#pragma unroll
      for (int nn = 0; nn < 8; ++nn) {
        const int d = nn * 16 + r;
#pragma unroll
        for (int kk = 0; kk < 2; ++kk) {
          const bf16x8 vf = *(const bf16x8*)(Vb + d * 64 + (((kk * 4 + g) ^ (d & 7)) * 8));
          o[nn] = __builtin_amdgcn_mfma_f32_16x16x32_bf16(pf[kk], vf, o[nn], 0, 0, 0);
        }
      }
      __builtin_amdgcn_s_setprio(0);
    }
    if (tt + 1 < te) {
      __syncthreads();   // B: all waves done with P (in Kl) and Vl before overwrite
      STAGE(tt + 1);
      __syncthreads();   // C: staged data visible
    }
  }
  // epilogue: reduce distributed s across the 16-lane row group
#pragma unroll
  for (int off = 1; off < 16; off <<= 1)
#pragma unroll
    for (int q = 0; q < 4; ++q) sl[q] += __shfl_xor(sl[q], off);
  const int row0 = wrow + 4 * g;         // row within this wave's q-tile
  if (s < 4) {  // single chunk: final output directly
#pragma unroll
    for (int nn = 0; nn < 8; ++nn)
#pragma unroll
      for (int q = 0; q < 4; ++q)
        yb[(long)(qt * 64 + row0 + q) * DIM + h * D + nn * 16 + r] = (bf16)(o[nn][q] / sl[q]);
  } else {
    const long part = (long)h * PPH + (pre_qt(qt) - 8) + ci;
    bf16* pob = po + part * 8192;
#pragma unroll
    for (int nn = 0; nn < 8; ++nn)
#pragma unroll
      for (int q = 0; q < 4; ++q)
        pob[(row0 + q) * 128 + nn * 16 + r] = (bf16)o[nn][q];
    if (r == 0) {
#pragma unroll
      for (int q = 0; q < 4; ++q) {
        pm[part * 64 + row0 + q] = m[q];
        ps[part * 64 + row0 + q] = sl[q];
      }
    }
  }
}

// Merge 2..8 KV-chunk partials per (qt>=8, h) -> yb. m already in log2 domain.
__global__ __launch_bounds__(256) void attn_reduce(const bf16* __restrict__ po,
                                                   const float* __restrict__ pm,
                                                   const float* __restrict__ ps,
                                                   bf16* __restrict__ yb) {
  const int qt = 8 + blockIdx.x, h = blockIdx.y;
  const int tid = threadIdx.x;
  const int row = tid >> 2, seg = (tid & 3) * 32;
  const int nch = (qt >> 3) + 1;
  const long base = (long)h * PPH + pre_qt(qt) - 8;
  float mm = -1e30f;
  for (int ci = 0; ci < nch; ++ci) mm = fmaxf(mm, pm[(base + ci) * 64 + row]);
  float den = 0.f;
  for (int ci = 0; ci < nch; ++ci)
    den += ps[(base + ci) * 64 + row] * exp2f(pm[(base + ci) * 64 + row] - mm);
  const float inv = 1.f / den;
  float acc[32] = {};
  for (int ci = 0; ci < nch; ++ci) {
    const float wq = exp2f(pm[(base + ci) * 64 + row] - mm) * inv;
    const bf16* src = po + (base + ci) * 8192 + row * 128 + seg;
#pragma unroll
    for (int j = 0; j < 32; j += 8) {
      const bf16x8 v = *(const bf16x8*)(src + j);
#pragma unroll
      for (int u = 0; u < 8; ++u) acc[j + u] += wq * (float)v[u];
    }
  }
  bf16 outv[32];
#pragma unroll
  for (int j = 0; j < 32; ++j) outv[j] = (bf16)acc[j];
  bf16* dst = yb + (long)(qt * 64 + row) * DIM + h * D + seg;
#pragma unroll
  for (int cc = 0; cc < 4; ++cc)
    *(int4*)(dst + cc * 8) = *(const int4*)&outv[cc * 8];
}

extern "C" void kernel_launch(void* const* d_in, const int* in_sizes, int n_in,
                              void* d_out, int out_size, void* d_ws, size_t ws_size,
                              hipStream_t stream) {
  const float* x     = (const float*)d_in[0];
  const float* ve    = (const float*)d_in[1];
  const float* qkv_w = (const float*)d_in[2];
  const float* lam   = (const float*)d_in[3];
  const float* cproj = (const float*)d_in[4];
  float* out = (float*)d_out;

  // Live-across-attn buffers first; dead staging (xb, wb) last, aliased by
  // the attention partials (po/pm/ps). qkv never exists in HBM.
  bf16* cb  = (bf16*)d_ws;                      // DIM*DIM
  bf16* qb  = cb + (long)DIM * DIM;             // H*T*D
  bf16* kb  = qb + (long)H * T * D;
  bf16* vt  = kb + (long)H * T * D;             // (h, d, t)
  bf16* yb  = vt + (long)H * T * D;             // T*DIM
  float2* tab = (float2*)(yb + (long)T * DIM);  // T*32 float2
  bf16* xb  = (bf16*)(tab + (long)T * 32);      // T*DIM   (dead after gemm_qkv)
  bf16* wb  = xb + (long)T * DIM;               // N3*DIM  (dead after gemm_qkv)
  bf16* po  = xb;                                     // PPH*H * 8192 bf16
  float* pm = (float*)(po + (long)PPH * H * 8192);    // PPH*H * 64
  float* ps = pm + (long)PPH * H * 64;                // PPH*H * 64

  const int NBX = T * DIM / 2048, NBW = N3 * DIM / 2048, NBC = DIM * DIM / 2048;
  prep<<<dim3(NBX + NBW + NBC + T * 32 / 256), 256, 0, stream>>>(x, qkv_w, cproj, xb, wb, cb, tab);

  gemm_qkv<<<dim3(N3 / 128, T / 64), 256, 0, stream>>>(xb, wb, tab, ve, lam, qb, kb, vt);
  attn<<<dim3(144 * H), 512, 0, stream>>>(qb, kb, vt, po, pm, ps, yb);
  attn_reduce<<<dim3(56, H), 256, 0, stream>>>(po, pm, ps, yb);
  gemm_bt<float><<<dim3(DIM / 64, T / 64), 256, 0, stream>>>(yb, cb, out, T, DIM, DIM);
}

// Round 18
// 129.655 us; speedup vs baseline: 1.0275x; 1.0275x over previous
//
#include <hip/hip_runtime.h>
#include <hip/hip_bf16.h>

using bf16 = __hip_bfloat16;
typedef __attribute__((ext_vector_type(8))) __bf16 bf16x8;
typedef __attribute__((ext_vector_type(4))) float f32x4;

static constexpr int T = 4096, DIM = 768, H = 6, D = 128, N3 = 2304;
static constexpr int PPH = 280;                    // stored partials per head (qt>=8)
static constexpr float kEps = 1.1920929e-07f;
static constexpr float kC1 = 0.12f * 1.44269504f;  // kScale*log2(e), folded into Q
static constexpr float kTHR = 11.54f;              // defer threshold, folded domain (= 8*log2e)

__device__ __forceinline__ void gll16(const bf16* g, bf16* l) {
  __builtin_amdgcn_global_load_lds((const __attribute__((address_space(1))) void*)g,
                                   (__attribute__((address_space(3))) void*)l, 16, 0, 0);
}

// sum_{q'<qt} ((q'>>3)+1)
__device__ __forceinline__ int pre_qt(int qt) {
  const int k = qt >> 3, rr = qt & 7;
  return qt + 4 * k * (k - 1) + rr * k;
}

// fused fp32->bf16 converts (x, qkv_w, cproj) + rotary table build
__global__ __launch_bounds__(256) void prep(const float* __restrict__ x,
                                            const float* __restrict__ qkv_w,
                                            const float* __restrict__ cproj,
                                            bf16* __restrict__ xb, bf16* __restrict__ wb,
                                            bf16* __restrict__ cb, float2* __restrict__ tab) {
  const int NBX = T * DIM / 2048, NBW = N3 * DIM / 2048, NBC = DIM * DIM / 2048;
  int b = blockIdx.x;
  const int tid = threadIdx.x;
  if (b < NBX + NBW + NBC) {
    const float* in;
    bf16* out;
    if (b < NBX) { in = x; out = xb; }
    else if (b < NBX + NBW) { in = qkv_w; out = wb; b -= NBX; }
    else { in = cproj; out = cb; b -= NBX + NBW; }
    const int i = (b * 256 + tid) * 8;
    const float4 a = *(const float4*)(in + i);
    const float4 c = *(const float4*)(in + i + 4);
    bf16 t[8] = {(bf16)a.x, (bf16)a.y, (bf16)a.z, (bf16)a.w,
                 (bf16)c.x, (bf16)c.y, (bf16)c.z, (bf16)c.w};
    *(int4*)(out + i) = *(const int4*)t;
  } else {
    b -= NBX + NBW + NBC;
    const int i = b * 256 + tid;  // T*32 total
    const int t = i >> 5, j = i & 31;
    const float af = exp2f(-10.f * (float)j * (1.f / 31.f));
    float s, c;
    sincosf((float)t * af, &s, &c);
    tab[i] = make_float2(c, s);
  }
}

// GEMM1 fused with qkv post-processing. Tile 64x128 = 64 t-rows x ONE head-slice
// (slice = blockIdx.x: 0-5 q-heads, 6-11 k-heads, 12-17 v-heads). After the
// K-loop, acc -> LDS tile [64][137] and the epilogue does RMS+rotary (q,k) or
// lambda-mix+transpose (v). qkv never touches HBM.
__global__ __launch_bounds__(256, 4) void gemm_qkv(const bf16* __restrict__ A,
                                                   const bf16* __restrict__ B,
                                                   const float2* __restrict__ tab,
                                                   const float* __restrict__ ve,
                                                   const float* __restrict__ lam,
                                                   bf16* __restrict__ qb,
                                                   bf16* __restrict__ kb,
                                                   bf16* __restrict__ vt) {
  __shared__ bf16 sh[12288];  // lA[64][64] @0 | lB[128][64] @4096; then tile[64][137]
  const int tid = threadIdx.x, lane = tid & 63, wid = tid >> 6;
  const int slice = blockIdx.x;         // 0..17
  const int brow = blockIdx.y * 64;
  const int bcol = slice * 128;
  const int wm = (wid >> 1) * 32, wn = (wid & 1) * 64;
  const int r = lane & 15, g = lane >> 4;
  f32x4 acc[2][4] = {};
  const int lrow = lane >> 3;
  const int scol = (lane & 7) * 8;
  const bf16* gA = A + (long)(brow + wid * 16 + lrow) * DIM + scol;
  const bf16* gB = B + (long)(bcol + wid * 32 + lrow) * DIM + scol;
  for (int k0 = 0; k0 < DIM; k0 += 64) {
    __syncthreads();
#pragma unroll
    for (int i = 0; i < 2; ++i)
      gll16(gA + (long)i * 8 * DIM + k0, sh + (wid * 16 + i * 8) * 64);
#pragma unroll
    for (int i = 0; i < 4; ++i)
      gll16(gB + (long)i * 8 * DIM + k0, sh + 4096 + (wid * 32 + i * 8) * 64);
    __syncthreads();
#pragma unroll
    for (int kk = 0; kk < 2; ++kk) {
      bf16x8 af[2], bfr[4];
#pragma unroll
      for (int m = 0; m < 2; ++m)
        af[m] = *(const bf16x8*)(sh + (wm + m * 16 + r) * 64 + kk * 32 + g * 8);
#pragma unroll
      for (int n = 0; n < 4; ++n)
        bfr[n] = *(const bf16x8*)(sh + 4096 + (wn + n * 16 + r) * 64 + kk * 32 + g * 8);
#pragma unroll
      for (int m = 0; m < 2; ++m)
#pragma unroll
        for (int n = 0; n < 4; ++n)
          acc[m][n] = __builtin_amdgcn_mfma_f32_16x16x32_bf16(af[m], bfr[n], acc[m][n], 0, 0, 0);
    }
  }
  __syncthreads();  // all waves done reading lA/lB before tile overlay
#pragma unroll
  for (int m = 0; m < 2; ++m)
#pragma unroll
    for (int n = 0; n < 4; ++n)
#pragma unroll
      for (int q = 0; q < 4; ++q)
        sh[(wm + m * 16 + g * 4 + q) * 137 + wn + n * 16 + r] = (bf16)acc[m][n][q];
  __syncthreads();
  const int type = slice / 6, h = slice % 6;
  if (type < 2) {  // q/k: RMS-norm + rotary. 4 threads/row, 16 (d, d+64) pairs each.
    const int row = tid >> 2, p0 = (tid & 3) * 16;
    const int t = brow + row;
    float x1[16], x2[16];
    float ss = 0.f;
#pragma unroll
    for (int j = 0; j < 16; ++j) {
      x1[j] = __bfloat162float(sh[row * 137 + p0 + j]);
      x2[j] = __bfloat162float(sh[row * 137 + p0 + 64 + j]);
      ss += x1[j] * x1[j] + x2[j] * x2[j];
    }
    ss += __shfl_xor(ss, 1);
    ss += __shfl_xor(ss, 2);
    const float sc = rsqrtf(ss * (1.f / 128.f) + kEps) * (type == 0 ? kC1 : 1.f);
    bf16 y1[16], y2[16];
#pragma unroll
    for (int j = 0; j < 16; ++j) {
      float c = 1.f, s = 0.f;
      if (p0 + j < 32) { const float2 cs = tab[t * 32 + p0 + j]; c = cs.x; s = cs.y; }
      const float a = x1[j] * sc, b = x2[j] * sc;
      y1[j] = (bf16)(a * c + b * s);
      y2[j] = (bf16)(b * c - a * s);
    }
    bf16* dst = (type == 0 ? qb : kb) + ((long)h * T + t) * D + p0;
    *(int4*)(dst) = *(const int4*)&y1[0];
    *(int4*)(dst + 8) = *(const int4*)&y1[8];
    *(int4*)(dst + 64) = *(const int4*)&y2[0];
    *(int4*)(dst + 72) = *(const int4*)&y2[8];
  } else {  // v: v = l0*v + l1*ve, then transpose to (h, d, t)
    const float l0 = lam[0], l1 = lam[1];
    const int row = tid >> 2, seg = (tid & 3) * 32;
    const float* vs = ve + (long)(brow + row) * DIM + h * D + seg;
#pragma unroll
    for (int j = 0; j < 32; j += 4) {
      const float4 e = *(const float4*)(vs + j);
      const float ef[4] = {e.x, e.y, e.z, e.w};
#pragma unroll
      for (int u = 0; u < 4; ++u) {
        const int c = seg + j + u;
        sh[row * 137 + c] = (bf16)(l0 * __bfloat162float(sh[row * 137 + c]) + l1 * ef[u]);
      }
    }
    __syncthreads();
    const int d = tid >> 1, half = tid & 1;
    bf16 outr[32];
#pragma unroll
    for (int j = 0; j < 32; ++j) outr[j] = sh[(half * 32 + j) * 137 + d];
    bf16* dst = vt + ((long)h * D + d) * T + brow + half * 32;
#pragma unroll
    for (int c = 0; c < 4; ++c)
      *(int4*)(dst + c * 8) = *(const int4*)&outr[c * 8];
  }
}

// Output projection GEMM: C(MxN) = A(MxK) * B(NxK)^T. BM=64 x BN=64 tile,
// 16KB LDS, grid (N/64, M/64) = 768 blocks -> ~3 blocks/CU.
template <typename CT>
__global__ __launch_bounds__(256, 4) void gemm_bt(const bf16* __restrict__ A,
                                                  const bf16* __restrict__ B,
                                                  CT* __restrict__ C,
                                                  int M, int N, int K) {
  __shared__ bf16 lA[64][64];
  __shared__ bf16 lB[64][64];
  const int tid = threadIdx.x, lane = tid & 63, wid = tid >> 6;
  const int brow = blockIdx.y * 64, bcol = blockIdx.x * 64;
  const int wm = (wid >> 1) * 32, wn = (wid & 1) * 32;
  const int r = lane & 15, g = lane >> 4;
  f32x4 acc[2][2] = {};
  const int lrow = lane >> 3;
  const int scol = (lane & 7) * 8;
  const bf16* gA = A + (long)(brow + wid * 16 + lrow) * K + scol;
  const bf16* gB = B + (long)(bcol + wid * 16 + lrow) * K + scol;
  for (int k0 = 0; k0 < K; k0 += 64) {
    __syncthreads();
#pragma unroll
    for (int i = 0; i < 2; ++i) {
      gll16(gA + (long)i * 8 * K + k0, &lA[wid * 16 + i * 8][0]);
      gll16(gB + (long)i * 8 * K + k0, &lB[wid * 16 + i * 8][0]);
    }
    __syncthreads();
#pragma unroll
    for (int kk = 0; kk < 2; ++kk) {
      bf16x8 af[2], bfr[2];
#pragma unroll
      for (int m = 0; m < 2; ++m)
        af[m] = *(const bf16x8*)&lA[wm + m * 16 + r][kk * 32 + g * 8];
#pragma unroll
      for (int n = 0; n < 2; ++n)
        bfr[n] = *(const bf16x8*)&lB[wn + n * 16 + r][kk * 32 + g * 8];
#pragma unroll
      for (int m = 0; m < 2; ++m)
#pragma unroll
        for (int n = 0; n < 2; ++n)
          acc[m][n] = __builtin_amdgcn_mfma_f32_16x16x32_bf16(af[m], bfr[n], acc[m][n], 0, 0, 0);
    }
  }
  const int crow = brow + wm + g * 4;
  const int ccol = bcol + wn + r;
#pragma unroll
  for (int m = 0; m < 2; ++m)
#pragma unroll
    for (int n = 0; n < 2; ++n)
#pragma unroll
      for (int q = 0; q < 4; ++q)
        C[(long)(crow + m * 16 + q) * N + ccol + n * 16] = (CT)acc[m][n][q];
}

// Flash-style causal attention. 512-thread block = 128-row q-supertile (8 waves,
// waves 0-3 -> q-tile 2s, waves 4-7 -> q-tile 2s+1) sharing one staged K/V tile.
// KVBLK=64 single-buffered gll16 staging, chunks of 8 tiles, 48KB LDS ->
// 3 blocks/CU. R12-proven 65.7us best. Ledger (all lose to this): 256thr(73),
// dbuf80KB(85.5), reg-stage(78.5), dbuf40KB/KVBLK32(67.4), P-alias-32KB(68.4).
__global__ __launch_bounds__(512, 4) void attn(const bf16* __restrict__ qb,
                                               const bf16* __restrict__ kb,
                                               const bf16* __restrict__ vt,
                                               bf16* __restrict__ po,
                                               float* __restrict__ pm,
                                               float* __restrict__ ps,
                                               bf16* __restrict__ yb) {
  __shared__ bf16 Kl[64][128];
  __shared__ bf16 Vl[128][64];
  __shared__ bf16 Pl[8][16][64];
  const int bid = blockIdx.x;
  const int h = bid % H;
  const int fi = bid / H;
  int s = 31, ci = 0, acc0 = 0;          // heavy-first band decode
  for (int ss = 31; ss >= 0; --ss) {
    const int n = (ss >> 2) + 1;
    if (fi < acc0 + n) { s = ss; ci = fi - acc0; break; }
    acc0 += n;
  }
  const int tid = threadIdx.x, lane = tid & 63, w = tid >> 6;  // w in 0..7
  const int r = lane & 15, g = lane >> 4;
  const int qt = 2 * s + (w >> 2);       // this wave's q-tile
  const int wrow = (w & 3) * 16;         // row offset within q-tile
  const int ts = ci * 8;
  const int te = min(ts + 8, 2 * s + 2);

  bf16x8 qf[4];
#pragma unroll
  for (int kk = 0; kk < 4; ++kk)
    qf[kk] = *(const bf16x8*)(qb + ((long)h * T + qt * 64 + wrow + r) * D + kk * 32 + g * 8);
  f32x4 o[8] = {};
  float m[4], sl[4];
#pragma unroll
  for (int q = 0; q < 4; ++q) { m[q] = -1e30f; sl[q] = 0.f; }

  auto STAGE = [&](int t) {
    const int kv0 = t * 64;
#pragma unroll
    for (int i = 0; i < 2; ++i) {
      const int seg = w * 2 + i;         // 16 segs of 1KB each for K and V
      {  // K: 64 rows x 128 cols; seg = 4 rows of 256B
        const int lr = seg * 4 + (lane >> 4);
        const int cs = (lane & 15) ^ (lr & 7);
        gll16(kb + ((long)h * T + kv0 + lr) * D + cs * 8,
              (bf16*)&Kl[0][0] + seg * 512);
      }
      {  // V: 128 rows x 64 cols; seg = 8 rows of 128B
        const int lr = seg * 8 + (lane >> 3);
        const int cs = (lane & 7) ^ (lr & 7);
        gll16(vt + ((long)h * D + lr) * T + kv0 + cs * 8,
              (bf16*)&Vl[0][0] + seg * 512);
      }
    }
  };

  STAGE(ts);
  __syncthreads();
  for (int tt = ts; tt < te; ++tt) {
    const bool act = (tt <= qt);         // wave-uniform; A-waves skip last tile
    if (act) {
      const bf16* Kb = (const bf16*)&Kl[0][0];
      const bf16* Vb = (const bf16*)&Vl[0][0];
      bf16* Pb = &Pl[w][0][0];
      f32x4 st4[4];
      __builtin_amdgcn_s_setprio(1);
#pragma unroll
      for (int stt = 0; stt < 4; ++stt) {
        f32x4 a = {};
        const int lrk = stt * 16 + r;
#pragma unroll
        for (int kk = 0; kk < 4; ++kk) {
          const bf16x8 kf = *(const bf16x8*)(Kb + lrk * 128 + (((kk * 4 + g) ^ (lrk & 7)) * 8));
          a = __builtin_amdgcn_mfma_f32_16x16x32_bf16(qf[kk], kf, a, 0, 0, 0);
        }
        st4[stt] = a;
      }
      __builtin_amdgcn_s_setprio(0);
      if (tt == qt) {  // diagonal tile: causal mask
        const int qgl = qt * 64 + wrow + 4 * g;
#pragma unroll
        for (int stt = 0; stt < 4; ++stt)
#pragma unroll
          for (int q = 0; q < 4; ++q)
            if (tt * 64 + stt * 16 + r > qgl + q) st4[stt][q] = -1e30f;
      }
      float mx[4];
#pragma unroll
      for (int q = 0; q < 4; ++q)
        mx[q] = fmaxf(fmaxf(st4[0][q], st4[1][q]), fmaxf(st4[2][q], st4[3][q]));
      const float dd = fmaxf(fmaxf(mx[0] - m[0], mx[1] - m[1]),
                             fmaxf(mx[2] - m[2], mx[3] - m[3]));
      if (__any(dd > kTHR)) {  // rare: full max-reduce + rescale
#pragma unroll
        for (int off = 1; off < 16; off <<= 1)
#pragma unroll
          for (int q = 0; q < 4; ++q) mx[q] = fmaxf(mx[q], __shfl_xor(mx[q], off));
#pragma unroll
        for (int q = 0; q < 4; ++q) {
          const float nm = fmaxf(m[q], mx[q]);
          const float al = exp2f(m[q] - nm);
          m[q] = nm;
          sl[q] *= al;
#pragma unroll
          for (int nn = 0; nn < 8; ++nn) o[nn][q] *= al;
        }
      }
      // P = exp2(st - m), scale pre-folded into Q. Explicit subtract (NOT fma
      // with precomputed m-term): masked rows have st=m=-1e30; fma residue can
      // reach +-2^74 -> exp2 -> inf -> 0*inf = NaN in the merge.
#pragma unroll
      for (int stt = 0; stt < 4; ++stt)
#pragma unroll
        for (int q = 0; q < 4; ++q)
          st4[stt][q] = exp2f(st4[stt][q] - m[q]);
#pragma unroll
      for (int q = 0; q < 4; ++q)
        sl[q] += (st4[0][q] + st4[1][q]) + (st4[2][q] + st4[3][q]);
#pragma unroll
      for (int stt = 0; stt < 4; ++stt)
#pragma unroll
        for (int q = 0; q < 4; ++q) {
          const int rw = 4 * g + q;
          Pb[rw * 64 + ((stt * 16 + r) ^ ((rw & 7) << 3))] = (bf16)st4[stt][q];
        }
      bf16x8 pf[2];
#pragma unroll
      for (int kk = 0; kk < 2; ++kk)
        pf[kk] = *(const bf16x8*)(Pb + r * 64 + (((kk * 4 + g) ^ (r & 7)) * 8));
      __builtin_amdgcn_s_setprio(1);
#pragma unroll
      for (int nn = 0; nn < 8; ++nn) {
        const int d = nn * 16 + r;
#pragma unroll
        for (int kk = 0; kk < 2; ++kk) {
          const bf16x8 vf = *(const bf16x8*)(Vb + d * 64 + (((kk * 4 + g) ^ (d & 7)) * 8));
          o[nn] = __builtin_amdgcn_mfma_f32_16x16x32_bf16(pf[kk], vf, o[nn], 0, 0, 0);
        }
      }
      __builtin_amdgcn_s_setprio(0);
    }
    if (tt + 1 < te) {
      __syncthreads();   // all waves done reading K/V before overwrite
      STAGE(tt + 1);
      __syncthreads();   // staged data visible
    }
  }
  // epilogue: reduce distributed s across the 16-lane row group
#pragma unroll
  for (int off = 1; off < 16; off <<= 1)
#pragma unroll
    for (int q = 0; q < 4; ++q) sl[q] += __shfl_xor(sl[q], off);
  const int row0 = wrow + 4 * g;         // row within this wave's q-tile
  if (s < 4) {  // single chunk: final output directly
#pragma unroll
    for (int nn = 0; nn < 8; ++nn)
#pragma unroll
      for (int q = 0; q < 4; ++q)
        yb[(long)(qt * 64 + row0 + q) * DIM + h * D + nn * 16 + r] = (bf16)(o[nn][q] / sl[q]);
  } else {
    const long part = (long)h * PPH + (pre_qt(qt) - 8) + ci;
    bf16* pob = po + part * 8192;
#pragma unroll
    for (int nn = 0; nn < 8; ++nn)
#pragma unroll
      for (int q = 0; q < 4; ++q)
        pob[(row0 + q) * 128 + nn * 16 + r] = (bf16)o[nn][q];
    if (r == 0) {
#pragma unroll
      for (int q = 0; q < 4; ++q) {
        pm[part * 64 + row0 + q] = m[q];
        ps[part * 64 + row0 + q] = sl[q];
      }
    }
  }
}

// Merge 2..8 KV-chunk partials per (qt>=8, h) -> yb. m already in log2 domain.
__global__ __launch_bounds__(256) void attn_reduce(const bf16* __restrict__ po,
                                                   const float* __restrict__ pm,
                                                   const float* __restrict__ ps,
                                                   bf16* __restrict__ yb) {
  const int qt = 8 + blockIdx.x, h = blockIdx.y;
  const int tid = threadIdx.x;
  const int row = tid >> 2, seg = (tid & 3) * 32;
  const int nch = (qt >> 3) + 1;
  const long base = (long)h * PPH + pre_qt(qt) - 8;
  float mm = -1e30f;
  for (int ci = 0; ci < nch; ++ci) mm = fmaxf(mm, pm[(base + ci) * 64 + row]);
  float den = 0.f;
  for (int ci = 0; ci < nch; ++ci)
    den += ps[(base + ci) * 64 + row] * exp2f(pm[(base + ci) * 64 + row] - mm);
  const float inv = 1.f / den;
  float acc[32] = {};
  for (int ci = 0; ci < nch; ++ci) {
    const float wq = exp2f(pm[(base + ci) * 64 + row] - mm) * inv;
    const bf16* src = po + (base + ci) * 8192 + row * 128 + seg;
#pragma unroll
    for (int j = 0; j < 32; j += 8) {
      const bf16x8 v = *(const bf16x8*)(src + j);
#pragma unroll
      for (int u = 0; u < 8; ++u) acc[j + u] += wq * (float)v[u];
    }
  }
  bf16 outv[32];
#pragma unroll
  for (int j = 0; j < 32; ++j) outv[j] = (bf16)acc[j];
  bf16* dst = yb + (long)(qt * 64 + row) * DIM + h * D + seg;
#pragma unroll
  for (int cc = 0; cc < 4; ++cc)
    *(int4*)(dst + cc * 8) = *(const int4*)&outv[cc * 8];
}

extern "C" void kernel_launch(void* const* d_in, const int* in_sizes, int n_in,
                              void* d_out, int out_size, void* d_ws, size_t ws_size,
                              hipStream_t stream) {
  const float* x     = (const float*)d_in[0];
  const float* ve    = (const float*)d_in[1];
  const float* qkv_w = (const float*)d_in[2];
  const float* lam   = (const float*)d_in[3];
  const float* cproj = (const float*)d_in[4];
  float* out = (float*)d_out;

  // Live-across-attn buffers first; dead staging (xb, wb) last, aliased by
  // the attention partials (po/pm/ps). qkv never exists in HBM.
  bf16* cb  = (bf16*)d_ws;                      // DIM*DIM
  bf16* qb  = cb + (long)DIM * DIM;             // H*T*D
  bf16* kb  = qb + (long)H * T * D;
  bf16* vt  = kb + (long)H * T * D;             // (h, d, t)
  bf16* yb  = vt + (long)H * T * D;             // T*DIM
  float2* tab = (float2*)(yb + (long)T * DIM);  // T*32 float2
  bf16* xb  = (bf16*)(tab + (long)T * 32);      // T*DIM   (dead after gemm_qkv)
  bf16* wb  = xb + (long)T * DIM;               // N3*DIM  (dead after gemm_qkv)
  bf16* po  = xb;                                     // PPH*H * 8192 bf16
  float* pm = (float*)(po + (long)PPH * H * 8192);    // PPH*H * 64
  float* ps = pm + (long)PPH * H * 64;                // PPH*H * 64

  const int NBX = T * DIM / 2048, NBW = N3 * DIM / 2048, NBC = DIM * DIM / 2048;
  prep<<<dim3(NBX + NBW + NBC + T * 32 / 256), 256, 0, stream>>>(x, qkv_w, cproj, xb, wb, cb, tab);

  gemm_qkv<<<dim3(N3 / 128, T / 64), 256, 0, stream>>>(xb, wb, tab, ve, lam, qb, kb, vt);
  attn<<<dim3(144 * H), 512, 0, stream>>>(qb, kb, vt, po, pm, ps, yb);
  attn_reduce<<<dim3(56, H), 256, 0, stream>>>(po, pm, ps, yb);
  gemm_bt<float><<<dim3(DIM / 64, T / 64), 256, 0, stream>>>(yb, cb, out, T, DIM, DIM);
}